// Round 23
// baseline (95.181 us; speedup 1.0000x reference)
//
#include <hip/hip_runtime.h>

#define D 16

typedef short bf16x8 __attribute__((ext_vector_type(8)));
typedef float f32x16 __attribute__((ext_vector_type(16)));
typedef float v2f __attribute__((ext_vector_type(2)));

// ---- DPP helpers (wave64) ----
template<int CTRL, int RMASK, bool BC>
__device__ __forceinline__ float dpp_add(float x) {
    int t = __builtin_amdgcn_update_dpp(0, __float_as_int(x), CTRL, RMASK, 0xF, BC);
    return x + __int_as_float(t);
}
template<int CTRL>
__device__ __forceinline__ float dpp_mov(float x) {   // zero-fill shift
    return __int_as_float(
        __builtin_amdgcn_update_dpp(0, __float_as_int(x), CTRL, 0xF, 0xF, false));
}

// Radix-4 inclusive scan: 4 chained movs instead of 6 (stage movs overlap).
// Stage A: x += shr1+shr2+shr3  (== two radix-2 stages; span-4 sliding sum)
// Stage B: x += shr4+shr8+shr12 (-> full 16-lane prefix; algebra verified)
// Then the verified bcast15/bcast31 stitches. Zero-fill clamping identical
// to the rounds-8..20 scan; plain-prefix math unchanged.
__device__ __forceinline__ float wave_iscan(float x) {
    {
        float m1 = dpp_mov<0x111>(x);   // row_shr:1
        float m2 = dpp_mov<0x112>(x);   // row_shr:2
        float m3 = dpp_mov<0x113>(x);   // row_shr:3
        x = (m1 + m2) + (x + m3);
    }
    {
        float m1 = dpp_mov<0x114>(x);   // row_shr:4
        float m2 = dpp_mov<0x118>(x);   // row_shr:8
        float m3 = dpp_mov<0x11C>(x);   // row_shr:12
        x = (m1 + m2) + (x + m3);
    }
    x = dpp_add<0x142, 0xA, false>(x);  // row_bcast:15
    x = dpp_add<0x143, 0xC, false>(x);  // row_bcast:31
    return x;
}

// f32 -> bf16 round-to-nearest-even
__device__ __forceinline__ short f2bf(float f) {
    unsigned u = __float_as_uint(f);
    unsigned r = u + 0x7FFFu + ((u >> 16) & 1u);
    return (short)(r >> 16);
}

// One wave per (pair,batch); r20 structure (83.4 us, verified): counted-wait
// scan pipeline (lgkmcnt(8)) + pinned ds_read prefetch. Changes vs r20:
// radix-4 iscan (4 chained movs) and B = (1-S) + W (1-S precomputed
// off-chain during the iscan).
__global__ __launch_bounds__(64, 1)
void sig_pde_kernel(const float* __restrict__ X, const float* __restrict__ Y,
                    float* __restrict__ out) {
    __shared__ float sinc[32 * 512];        // 64 KB (inc-1) block, swizzled

    const int idx  = blockIdx.x;
    const int pair = idx >> 7;              // 0: XX, 1: YY, 2: XY
    const int a    = idx & 127;
    const float* Pp = (pair == 1) ? Y : X;  // row operand (dX)
    const float* Qp = (pair == 0) ? X : Y;  // col operand (dY)
    const float* prow = Pp + (size_t)a * 512 * D;
    const float* qrow = Qp + (size_t)a * 512 * D;

    const int l  = threadIdx.x;
    const int lm = l & 31;
    const int kh = l >> 5;                  // K-half of the fragment
    const int d0 = kh * 8;                  // this lane's dim offset
    const bool lane0 = (l == 0);

    // ---- B fragments: 16 column tiles of dY, resident in registers ----
    bf16x8 Bf[16];
    #pragma unroll
    for (int n = 0; n < 16; ++n) {
        int jj = 32 * n + lm - 1;
        if (jj < 0) jj = 0;                 // col 0 garbage (masked in scan)
        const float4* y1 = (const float4*)(qrow + (size_t)(jj + 1) * D + d0);
        const float4* y0 = (const float4*)(qrow + (size_t)jj * D + d0);
        float4 h1 = y1[0], h0 = y0[0], g1 = y1[1], g0 = y0[1];
        bf16x8 f;
        f[0] = f2bf(h1.x - h0.x); f[1] = f2bf(h1.y - h0.y);
        f[2] = f2bf(h1.z - h0.z); f[3] = f2bf(h1.w - h0.w);
        f[4] = f2bf(g1.x - g0.x); f[5] = f2bf(g1.y - g0.y);
        f[6] = f2bf(g1.z - g0.z); f[7] = f2bf(g1.w - g0.w);
        Bf[n] = f;
    }

    auto loadA = [&](int b) -> bf16x8 {
        int ii = 32 * b + lm - 1;
        if (ii < 0) ii = 0;                 // row 0 garbage (never scanned)
        const float4* x1 = (const float4*)(prow + (size_t)(ii + 1) * D + d0);
        const float4* x0 = (const float4*)(prow + (size_t)ii * D + d0);
        float4 h1 = x1[0], h0 = x0[0], g1 = x1[1], g0 = x0[1];
        bf16x8 f;
        f[0] = f2bf(h1.x - h0.x); f[1] = f2bf(h1.y - h0.y);
        f[2] = f2bf(h1.z - h0.z); f[3] = f2bf(h1.w - h0.w);
        f[4] = f2bf(g1.x - g0.x); f[5] = f2bf(g1.y - g0.y);
        f[6] = f2bf(g1.z - g0.z); f[7] = f2bf(g1.w - g0.w);
        return f;
    };

    const int rot = (l >> 2) & 7;           // read-side rotation (0-conflict)
    float* wbase = sinc + kh * 2048;

    // persistent per-lane LDS byte addresses for the 8 swizzled e-reads
    unsigned eaddr[8];
    #pragma unroll
    for (int m = 0; m < 8; ++m)
        eaddr[m] = (unsigned)(size_t)((const char*)sinc
                                      + (8 * l + ((m + rot) & 7)) * 4);

    // ---- scan state ----
    float s[8];
    #pragma unroll
    for (int m = 0; m < 8; ++m) s[m] = 0.0f;   // K[0][j] = 1 = B + 0
    float B = 1.0f;

    v2f ghA[8], ghB[8];
    float eA[8], eB[8];

    const f32x16 accC = {-1.f,-1.f,-1.f,-1.f,-1.f,-1.f,-1.f,-1.f,
                         -1.f,-1.f,-1.f,-1.f,-1.f,-1.f,-1.f,-1.f};

// counted wait: everything except the 8 newest DS ops (the prefetch just
// issued) is complete -> previous row's buffer ready, pipe never drains.
#define WAIT8() do {                                                          \
        asm volatile("s_waitcnt lgkmcnt(8)" ::: "memory");                    \
        __builtin_amdgcn_sched_barrier(0);                                    \
    } while (0)

#define PREFA(BUF, RR) do {                                                   \
        asm volatile("ds_read_b32 %0, %1 offset:%c2"                          \
                     : "=v"(BUF[0]) : "v"(eaddr[0]), "i"((RR) * 2048));       \
        asm volatile("ds_read_b32 %0, %1 offset:%c2"                          \
                     : "=v"(BUF[1]) : "v"(eaddr[1]), "i"((RR) * 2048));       \
        asm volatile("ds_read_b32 %0, %1 offset:%c2"                          \
                     : "=v"(BUF[2]) : "v"(eaddr[2]), "i"((RR) * 2048));       \
        asm volatile("ds_read_b32 %0, %1 offset:%c2"                          \
                     : "=v"(BUF[3]) : "v"(eaddr[3]), "i"((RR) * 2048));       \
        asm volatile("ds_read_b32 %0, %1 offset:%c2"                          \
                     : "=v"(BUF[4]) : "v"(eaddr[4]), "i"((RR) * 2048));       \
        asm volatile("ds_read_b32 %0, %1 offset:%c2"                          \
                     : "=v"(BUF[5]) : "v"(eaddr[5]), "i"((RR) * 2048));       \
        asm volatile("ds_read_b32 %0, %1 offset:%c2"                          \
                     : "=v"(BUF[6]) : "v"(eaddr[6]), "i"((RR) * 2048));       \
        asm volatile("ds_read_b32 %0, %1 offset:%c2"                          \
                     : "=v"(BUF[7]) : "v"(eaddr[7]), "i"((RR) * 2048));       \
    } while (0)

#define GHBUILD(GH, E) do {                                                   \
        float p0_ = E[0] + 1.0f;  p0_ = lane0 ? 0.0f : p0_;                   \
        float c0_ = lane0 ? 0.0f : s[0];                                      \
        GH[0][0] = p0_; GH[0][1] = c0_;                                       \
        _Pragma("unroll")                                                     \
        for (int m_ = 1; m_ < 8; ++m_) {                                      \
            v2f pc_;                                                          \
            pc_[0] = E[m_] + 1.0f;                                            \
            pc_[1] = fmaf(s[m_ - 1], E[m_], s[m_]);                          \
            GH[m_] = GH[m_ - 1] + pc_;                                        \
        }                                                                     \
    } while (0)

#define SFMA(GH) do {                                                         \
        _Pragma("unroll")                                                     \
        for (int m_ = 0; m_ < 8; ++m_)                                        \
            s[m_] = fmaf(B, GH[m_][0], GH[m_][1]);                            \
    } while (0)

// row step: prefetch row RP into EFREE (top), counted wait, consume GHC,
// build GHN (row r+1) from EREADY (its reads are now complete).
// 1-S precomputes off-chain while the iscan runs; B = (1-S) + W.
#define STEP1(GHC, GHN, EFREE, EREADY, RP) do {                               \
        PREFA(EFREE, RP);                                                     \
        WAIT8();                                                              \
        SFMA(GHC);                                                            \
        float S_ = s[7];                                                      \
        float onemS_ = 1.0f - S_;                                             \
        float W_ = wave_iscan(S_);                                            \
        GHBUILD(GHN, EREADY);                                                 \
        B = onemS_ + W_;                                                      \
    } while (0)

// scan tile rows FROM..31 (at block boundary the final GH build consumes a
// duplicated row-31 buffer; that GH is overwritten by the next prologue
// before any use -- provably dead).
#define SCAN_BLOCK(FROM) do {                                                 \
        PREFA(eA, (FROM));                                                    \
        PREFA(eB, (FROM) + 1);                                                \
        WAIT8();                    /* eA ready (eB is the newest 8) */       \
        GHBUILD(ghA, eA);                                                     \
        _Pragma("unroll")                                                     \
        for (int r_ = (FROM); r_ <= 31; ++r_) {                               \
            const int rp_ = (r_ + 2 <= 31) ? r_ + 2 : 31;                     \
            if (((r_ - (FROM)) & 1) == 0) STEP1(ghA, ghB, eA, eB, rp_);       \
            else                          STEP1(ghB, ghA, eB, eA, rp_);       \
        }                                                                     \
    } while (0)

    bf16x8 Acur = loadA(0);

    for (int b = 0; b < 16; ++b) {
        // ---- GEMM phase: (inc-1) rows 32b..32b+31, all 512 cols ----
        #pragma unroll
        for (int n = 0; n < 16; ++n) {
            f32x16 acc = __builtin_amdgcn_mfma_f32_32x32x16_bf16(Acur, Bf[n], accC, 0, 0, 0);
            float* p = wbase + 32 * n + (lm & ~7) + (((l & 7) + n) & 7);
            #pragma unroll
            for (int r = 0; r < 16; ++r)
                p[(r & 3) * 512 + (r >> 2) * 4096] = acc[r];
        }
        if (b < 15) Acur = loadA(b + 1);    // global prefetch under the scan

        // ---- scan phase (block 0 skips grid row 0) ----
        if (b == 0) SCAN_BLOCK(1);
        else        SCAN_BLOCK(0);
    }

#undef SCAN_BLOCK
#undef STEP1
#undef SFMA
#undef GHBUILD
#undef PREFA
#undef WAIT8

    // K[511][511] = lane 63: B + s[7]
    if (l == 63) out[idx] = B + s[7];
}

__global__ void sig_reduce_kernel(const float* __restrict__ ws,
                                  float* __restrict__ out) {
    const int a = threadIdx.x;  // 128 threads
    float v = ws[a] + ws[128 + a] - 2.0f * ws[256 + a];
    #pragma unroll
    for (int off = 32; off >= 1; off >>= 1) v += __shfl_down(v, off, 64);
    __shared__ float partial[2];
    if ((a & 63) == 0) partial[a >> 6] = v;
    __syncthreads();
    if (a == 0) out[0] = (partial[0] + partial[1]) * (1.0f / 128.0f);
}

extern "C" void kernel_launch(void* const* d_in, const int* in_sizes, int n_in,
                              void* d_out, int out_size, void* d_ws, size_t ws_size,
                              hipStream_t stream) {
    const float* X = (const float*)d_in[0];
    const float* Y = (const float*)d_in[1];
    float* out = (float*)d_out;
    float* ws  = (float*)d_ws;   // 384 floats: [pair*128 + a]

    sig_pde_kernel<<<dim3(384), dim3(64), 0, stream>>>(X, Y, ws);
    sig_reduce_kernel<<<dim3(1), dim3(128), 0, stream>>>(ws, out);
}